// Round 8
// baseline (259.258 us; speedup 1.0000x reference)
//
#include <hip/hip_runtime.h>

constexpr int BLK = 256;

// Compiler-proof IEEE f32 rn ops (inline asm: no fusion/reassociation
// beyond what is written).
__device__ __forceinline__ float mul_rn(float a, float b) {
    float r; asm("v_mul_f32 %0, %1, %2" : "=v"(r) : "v"(a), "v"(b)); return r;
}
__device__ __forceinline__ float add_rn(float a, float b) {
    float r; asm("v_add_f32 %0, %1, %2" : "=v"(r) : "v"(a), "v"(b)); return r;
}
__device__ __forceinline__ float sub_rn(float a, float b) {
    float r; asm("v_sub_f32 %0, %1, %2" : "=v"(r) : "v"(a), "v"(b)); return r;
}
__device__ __forceinline__ float fma_rn(float a, float b, float c) {
    float r; asm("v_fma_f32 %0, %1, %2, %3"
                 : "=v"(r) : "v"(a), "v"(b), "v"(c)); return r;
}

// Ascending FMA chain from zero — matches the np/XLA-lowered dot rounding:
//   fma(a2,b2, fma(a1,b1, rn(a0*b0)))
// Do not reassociate; do not let the compiler contract it differently.
__device__ __forceinline__ float dot3_fma_asc(float a0, float a1, float a2,
                                              float b0, float b1, float b2) {
    return fma_rn(a2, b2, fma_rn(a1, b1, mul_rn(a0, b0)));
}

// Round-8 experiment: L2-BYPASS loads (sc0 sc1 nt).
// Evidence: R6's nt loads cut 77.6 -> 55.9 us but FETCH_SIZE stayed ~108 GB
// (L3 still serves half) — the win was evict-priority, not re-sourcing.
// Read stream now 3.86 TB/s with HBM at 31% and L3 well under its ceiling;
// VALU 12.5%, occupancy 68%, latency can't bind (Little's law: 17x margin).
// Remaining shared resource: the L2 miss/fill path — 216 MB streaming
// through 32 MB aggregate L2 allocates+evicts on ~every access. sc1 scopes
// loads past L2; sc0 past L1; nt keeps evict-first. Builtins can't express
// sc bits -> inline asm. Scalar dword loads (alignment-safe at 4-B-aligned
// stride-36 records; R5 proved VMEM count is not the limiter).
// Rule #18: consumers can be hoisted past an inline-asm s_waitcnt —
// sched_barrier(0) after the waitcnt is mandatory.
__device__ __forceinline__ void load9_bypass(const float* __restrict__ p,
                                             float* d) {
    float a0, a1, a2, a3, a4, a5, a6, a7, a8;
    asm volatile(
        "global_load_dword %0, %9, off sc0 sc1 nt\n\t"
        "global_load_dword %1, %9, off offset:4 sc0 sc1 nt\n\t"
        "global_load_dword %2, %9, off offset:8 sc0 sc1 nt\n\t"
        "global_load_dword %3, %9, off offset:12 sc0 sc1 nt\n\t"
        "global_load_dword %4, %9, off offset:16 sc0 sc1 nt\n\t"
        "global_load_dword %5, %9, off offset:20 sc0 sc1 nt\n\t"
        "global_load_dword %6, %9, off offset:24 sc0 sc1 nt\n\t"
        "global_load_dword %7, %9, off offset:28 sc0 sc1 nt\n\t"
        "global_load_dword %8, %9, off offset:32 sc0 sc1 nt"
        : "=&v"(a0), "=&v"(a1), "=&v"(a2), "=&v"(a3), "=&v"(a4),
          "=&v"(a5), "=&v"(a6), "=&v"(a7), "=&v"(a8)
        : "v"(p)
        : "memory");
    d[0] = a0; d[1] = a1; d[2] = a2; d[3] = a3; d[4] = a4;
    d[5] = a5; d[6] = a6; d[7] = a7; d[8] = a8;
}

__global__ __launch_bounds__(BLK, 8) void so3_nll_kernel(
    const float* __restrict__ C_est,
    const float* __restrict__ C_tgt,
    const float* __restrict__ Rinv,
    float* __restrict__ out,
    int B)
{
    const int i_raw = blockIdx.x * BLK + threadIdx.x;
    const int i     = min(i_raw, B - 1);     // clamp: loads always in-bounds
    const size_t base = (size_t)i * 9;

    float E[9], T[9], R[9];
    load9_bypass(C_est + base, E);
    load9_bypass(C_tgt + base, T);
    load9_bypass(Rinv  + base, R);

    // Drain all loads, then fence the scheduler so no consumer is hoisted
    // above the wait (rule #18).
    asm volatile("s_waitcnt vmcnt(0)" ::: "memory");
    __builtin_amdgcn_sched_barrier(0);

    // ---- chaotic chain: must match the np ref's f32 rounding ----
    float d00 = dot3_fma_asc(E[0],E[1],E[2], T[0],T[1],T[2]);
    float d11 = dot3_fma_asc(E[3],E[4],E[5], T[3],T[4],T[5]);
    float d22 = dot3_fma_asc(E[6],E[7],E[8], T[6],T[7],T[8]);

    float tr = add_rn(add_rn(d00, d11), d22);    // (d00+d11)+d22
    float ca = 0.5f * sub_rn(tr, 1.0f);          // *0.5 exact
    constexpr float HI = 1.0f - 1e-7f;           // 0x3F7FFFFE == np bound
    ca = fminf(fmaxf(ca, -HI), HI);
    float angle = acosf(ca);
    float sa    = sinf(angle);
    // clamp => angle >= ~4.9e-4 > 1e-6: reference Taylor branch is dead
    float coef = (0.5f * angle) / sa;

    // ---- vee path: same chain for consistency ----
    float d01 = dot3_fma_asc(E[0],E[1],E[2], T[3],T[4],T[5]);
    float d02 = dot3_fma_asc(E[0],E[1],E[2], T[6],T[7],T[8]);
    float d10 = dot3_fma_asc(E[3],E[4],E[5], T[0],T[1],T[2]);
    float d12 = dot3_fma_asc(E[3],E[4],E[5], T[6],T[7],T[8]);
    float d20 = dot3_fma_asc(E[6],E[7],E[8], T[0],T[1],T[2]);
    float d21 = dot3_fma_asc(E[6],E[7],E[8], T[3],T[4],T[5]);

    float r0 = coef * sub_rn(d21, d12);
    float r1 = coef * sub_rn(d02, d20);
    float r2 = coef * sub_rn(d10, d01);

    // ---- well-conditioned tail: plain f32 ----
    float w = 0.5f * (r0 * ((R[0]*r0 + R[1]*r1) + R[2]*r2) +
                      r1 * ((R[3]*r0 + R[4]*r1) + R[5]*r2) +
                      r2 * ((R[6]*r0 + R[7]*r1) + R[8]*r2));

    float det = R[0] * (R[4]*R[8] - R[5]*R[7])
              - R[1] * (R[3]*R[8] - R[5]*R[6])
              + R[2] * (R[3]*R[7] - R[4]*R[6]);

    if (i_raw < B)
        __builtin_nontemporal_store(w - 0.5f * logf(det), out + i_raw);
}

extern "C" void kernel_launch(void* const* d_in, const int* in_sizes, int n_in,
                              void* d_out, int out_size, void* d_ws, size_t ws_size,
                              hipStream_t stream) {
    const float* C_est = (const float*)d_in[0];
    const float* C_tgt = (const float*)d_in[1];
    const float* Rinv  = (const float*)d_in[2];
    float* out = (float*)d_out;

    const int B = in_sizes[0] / 9;
    const int blocks = (B + BLK - 1) / BLK;
    so3_nll_kernel<<<blocks, BLK, 0, stream>>>(C_est, C_tgt, Rinv, out, B);
}